// Round 6
// baseline (64.996 us; speedup 1.0000x reference)
//
#include <hip/hip_runtime.h>

// AffinityFeature: out[b][a][h][w] = relu(cos(feat[b,:,h,w], feat[b,:,h+dh,w+dw])), 0 if OOB.
// a: 0:NW 1:N 2:NE 3:W 4:E 5:SW 6:S 7:SE. Symmetric: compute E,S,SE,SW per
// pixel, scatter mirrors (W,N,NW,NE) to the neighbor's location.
// Structure (R5 + depth-3 prefetch FIFO): 8x64-px block, 2 px/thread,
// LDS double-buffered channel slices; global load for channel c+3 issued in
// iteration c -> ~2.3 iterations of latency cover (T3/T4 counted-prefetch).

#define AF_B 4
#define AF_C 32
#define AF_H 256
#define AF_W 512
#define AF_EPS 1e-12f
#define AF_PLANE ((size_t)AF_H * AF_W)

#define LROW 72     // staged floats per row: cols [w0-4, w0+68)
#define LROWS 9     // staged rows: h0 .. h0+8
#define NSLOT 162   // LROWS * LROW / 4 float4 slots
#define PFD 3       // prefetch depth in channels

__global__ __launch_bounds__(256) void affinity_pf_kernel(const float* __restrict__ f,
                                                          float* __restrict__ out) {
    __shared__ float tile[2][LROWS][LROW];   // 5.2 KB

    // XCD-aware swizzle: 1024 blocks -> 128-block contiguous slab per XCD
    const int cpx = gridDim.x >> 3;
    const int bid = ((int)blockIdx.x & 7) * cpx + ((int)blockIdx.x >> 3);
    const int wband = bid & 7;            // 8 w-bands of 64 cols
    const int hband = (bid >> 3) & 31;    // 32 h-bands of 8 rows
    const int b = bid >> 8;               // 4 batches

    const int h0 = hband << 3;
    const int wb0 = wband << 6;
    const int tid = (int)threadIdx.x;

    // ---- staging descriptor: slot -> (srow, scol4) ----
    const int slot = tid;
    const int srow = slot / 18;                    // 0..8 (18 float4 per row)
    const int scol4 = slot - srow * 18;            // 0..17
    const int gcol = wb0 + (scol4 << 2) - 4;       // global col of chunk
    const int grow = h0 + srow;                    // global row
    const bool sv = (slot < NSLOT) && (gcol >= 0) && (gcol < AF_W) && (grow < AF_H);
    const size_t goff = (size_t)(sv ? grow : 0) * AF_W + (sv ? gcol : 0);
    const float* gsrc = f + (size_t)b * AF_C * AF_PLANE + goff;
    float* const lslotA = &tile[0][0][0] + (slot << 2);
    float* const lslotB = &tile[1][0][0] + (slot << 2);

    // pre-zero both buffers (halo slots stay 0 for all channels)
    if (slot < NSLOT) {
        *(float4*)lslotA = make_float4(0.f, 0.f, 0.f, 0.f);
        *(float4*)lslotB = make_float4(0.f, 0.f, 0.f, 0.f);
    }

    // ---- prologue: fifo[k%3] holds channel k; stage ch0 into LDS buf0 ----
    float4 fifo[PFD];
    if (sv) {
        fifo[0] = *(const float4*)(gsrc + 0 * AF_PLANE);
        fifo[1] = *(const float4*)(gsrc + 1 * AF_PLANE);
        fifo[2] = *(const float4*)(gsrc + 2 * AF_PLANE);
        *(float4*)lslotA = fifo[0];
    }
    __syncthreads();

    // ---- compute descriptor: 2 px/thread ----
    const int g = tid & 31;          // col-pair group
    const int r = tid >> 5;          // row in tile 0..7
    const int lcol = (g << 1) + 4;   // LDS col of w0
    const int h = h0 + r;
    const int w0 = wb0 + (g << 1);

    float ssq0=0, ssq1=0, ssqR=0;
    float nsq0=0, nsq1=0, nsqL=0, nsqR=0;
    float dE0=0, dE1=0, dS0=0, dS1=0, dSE0=0, dSE1=0, dSW0=0, dSW1=0;

#pragma unroll
    for (int c = 0; c < AF_C; ++c) {
        // issue load for channel c+PFD (consumed PFD iterations from now)
        if (sv && (c + PFD < AF_C))
            fifo[c % PFD] = *(const float4*)(gsrc + (size_t)(c + PFD) * AF_PLANE);

        // compute channel c from current LDS buffer
        const float (*cur)[LROW] = tile[c & 1];
        const float2 cc = *(const float2*)&cur[r][lcol];        // center w0,w0+1
        const float2 cs = *(const float2*)&cur[r + 1][lcol];    // south  w0,w0+1
        const float ccR = cur[r][lcol + 2];                     // center w0+2
        const float csR = cur[r + 1][lcol + 2];                 // south  w0+2
        const float csL = cur[r + 1][lcol - 1];                 // south  w0-1

        ssq0 += cc.x*cc.x; ssq1 += cc.y*cc.y; ssqR += ccR*ccR;
        nsq0 += cs.x*cs.x; nsq1 += cs.y*cs.y; nsqL += csL*csL; nsqR += csR*csR;
        dE0  += cc.x*cc.y; dE1  += cc.y*ccR;
        dS0  += cc.x*cs.x; dS1  += cc.y*cs.y;
        dSE0 += cc.x*cs.y; dSE1 += cc.y*csR;
        dSW0 += cc.x*csL;  dSW1 += cc.y*cs.x;

        // write channel c+1 (loaded PFD-1 iterations ago) into the freed buffer
        if (c + 1 < AF_C) {
            if (sv) {
                float* dst = ((c + 1) & 1) ? lslotB : lslotA;
                *(float4*)dst = fifo[(c + 1) % PFD];
            }
            __syncthreads();
        }
    }

    const float ic0 = 1.0f / fmaxf(sqrtf(ssq0), AF_EPS);
    const float ic1 = 1.0f / fmaxf(sqrtf(ssq1), AF_EPS);
    const float icR = 1.0f / fmaxf(sqrtf(ssqR), AF_EPS);
    const float is0 = 1.0f / fmaxf(sqrtf(nsq0), AF_EPS);
    const float is1 = 1.0f / fmaxf(sqrtf(nsq1), AF_EPS);
    const float isL = 1.0f / fmaxf(sqrtf(nsqL), AF_EPS);
    const float isR = 1.0f / fmaxf(sqrtf(nsqR), AF_EPS);

    const float E0  = fmaxf(dE0 *ic0*ic1, 0.0f);
    const float E1  = fmaxf(dE1 *ic1*icR, 0.0f);
    const float S0  = fmaxf(dS0 *ic0*is0, 0.0f);
    const float S1  = fmaxf(dS1 *ic1*is1, 0.0f);
    const float SE0 = fmaxf(dSE0*ic0*is1, 0.0f);
    const float SE1 = fmaxf(dSE1*ic1*isR, 0.0f);
    const float SW0 = fmaxf(dSW0*ic0*isL, 0.0f);
    const float SW1 = fmaxf(dSW1*ic1*is0, 0.0f);

    float* obase = out + (size_t)b * 8 * AF_PLANE + (size_t)h * AF_W + w0;
    const bool vR2 = (w0 + 2) < AF_W;
    const bool vL  = w0 > 0;
    const bool vS  = (h + 1) < AF_H;

    // forward channels at (h, w0..w0+1)
    *(float2*)(obase + 4*AF_PLANE) = make_float2(E0, E1);
    *(float2*)(obase + 5*AF_PLANE) = make_float2(SW0, SW1);
    *(float2*)(obase + 6*AF_PLANE) = make_float2(S0, S1);
    *(float2*)(obase + 7*AF_PLANE) = make_float2(SE0, SE1);

    // a=3 (W): W(h,w) = E(h,w-1)
    float* p3 = obase + 3*AF_PLANE;
    p3[1] = E0;
    if (vR2) p3[2] = E1;
    if (!vL) p3[0] = 0.0f;

    if (vS) {
        float* onb = obase + AF_W;      // row h+1
        *(float2*)(onb + 1*AF_PLANE) = make_float2(S0, S1);   // N
        float* p0 = onb;                // NW(h+1,w) = SE(h,w-1)
        p0[1] = SE0;
        if (vR2) p0[2] = SE1;
        if (!vL) p0[0] = 0.0f;
        float* p2 = onb + 2*AF_PLANE;   // NE(h+1,w) = SW(h,w+1)
        if (vL) p2[-1] = SW0;
        p2[0] = SW1;
        if (!vR2) p2[1] = 0.0f;
    }

    if (h == 0) {                        // N/NW/NE at h=0 all OOB
        float* oz = out + (size_t)b * 8 * AF_PLANE + w0;
        const float2 z2 = make_float2(0.0f, 0.0f);
        *(float2*)(oz + 0*AF_PLANE) = z2;
        *(float2*)(oz + 1*AF_PLANE) = z2;
        *(float2*)(oz + 2*AF_PLANE) = z2;
    }
}

extern "C" void kernel_launch(void* const* d_in, const int* in_sizes, int n_in,
                              void* d_out, int out_size, void* d_ws, size_t ws_size,
                              hipStream_t stream) {
    const float* f = (const float*)d_in[0];
    float* out = (float*)d_out;
    // grid = 4 batches x 32 h-bands x 8 w-bands = 1024 blocks of 256 threads
    affinity_pf_kernel<<<1024, 256, 0, stream>>>(f, out);
}

// Round 7
// 44.808 us; speedup vs baseline: 1.4505x; 1.4505x over previous
//
#include <hip/hip_runtime.h>

// AffinityFeature: out[b][a][h][w] = relu(cos(feat[b,:,h,w], feat[b,:,h+dh,w+dw])), 0 if OOB.
// a: 0:NW 1:N 2:NE 3:W 4:E 5:SW 6:S 7:SE. Symmetric: compute E,S,SE,SW per
// pixel, scatter mirrors to the neighbor's location.
// R7 structure: 8x64-px tile, 2 px/thread, BULK staging — 8 channels per
// phase (6 independent dwordx4/thread -> LDS), 1 barrier per stage/compute
// phase (7 total vs R5/R6's 32). Kills the per-channel vmcnt(0) barrier
// drain that serialized R5/R6.

#define AF_B 4
#define AF_C 32
#define AF_H 256
#define AF_W 512
#define AF_EPS 1e-12f
#define AF_PLANE ((size_t)AF_H * AF_W)

#define LROW 72            // staged cols: wb0-4 .. wb0+67
#define LROWS 9            // staged rows: h0 .. h0+8
#define CHP 8              // channels per phase
#define NPHASE 4
#define SLOTS_PER_CH 162   // 9 rows * 18 float4
#define SLOTS_PHASE (CHP * SLOTS_PER_CH)   // 1296
#define SITER 6            // ceil(1296/256)

__global__ __launch_bounds__(256) void affinity_bulk_kernel(const float* __restrict__ f,
                                                            float* __restrict__ out) {
    __shared__ float tile[CHP][LROWS][LROW];   // 20736 B

    // XCD-aware swizzle: 1024 blocks -> 128-block contiguous slab per XCD
    const int cpx = gridDim.x >> 3;
    const int bid = ((int)blockIdx.x & 7) * cpx + ((int)blockIdx.x >> 3);
    const int wband = bid & 7;            // 8 w-bands of 64 cols
    const int hband = (bid >> 3) & 31;    // 32 h-bands of 8 rows
    const int b = bid >> 8;               // 4 batches

    const int h0 = hband << 3;
    const int wb0 = wband << 6;
    const int tid = (int)threadIdx.x;

    const float* fbase = f + (size_t)b * AF_C * AF_PLANE;

    // ---- per-thread staging descriptors (identical across phases) ----
    int lofs[SITER];
    const float* gptr[SITER];
    bool act[SITER], val[SITER];
#pragma unroll
    for (int k = 0; k < SITER; ++k) {
        const int slot = tid + (k << 8);
        act[k] = slot < SLOTS_PHASE;
        const int ch = slot / SLOTS_PER_CH;          // 0..7
        const int rem = slot - ch * SLOTS_PER_CH;
        const int srow = rem / 18;                   // 0..8
        const int sc4 = rem - srow * 18;             // 0..17
        const int gcol = wb0 + (sc4 << 2) - 4;
        const int grow = h0 + srow;
        val[k] = act[k] && (gcol >= 0) && (gcol < AF_W) && (grow < AF_H);
        lofs[k] = slot << 2;                         // dword offset in tile
        gptr[k] = fbase + (size_t)ch * AF_PLANE
                + (size_t)(val[k] ? grow : 0) * AF_W + (val[k] ? gcol : 0);
    }

    // ---- compute descriptor: 2 px/thread ----
    const int g = tid & 31;
    const int r = tid >> 5;
    const int lcol = (g << 1) + 4;
    const int h = h0 + r;
    const int w0 = wb0 + (g << 1);

    float ssq0=0, ssq1=0, ssqR=0;
    float nsq0=0, nsq1=0, nsqL=0, nsqR=0;
    float dE0=0, dE1=0, dS0=0, dS1=0, dSE0=0, dSE1=0, dSW0=0, dSW1=0;

    for (int p = 0; p < NPHASE; ++p) {
        // ---- bulk stage: 6 independent dwordx4 -> regs -> LDS ----
        float4 v[SITER];
        const size_t chofs = (size_t)p * CHP * AF_PLANE;
#pragma unroll
        for (int k = 0; k < SITER; ++k)
            if (val[k]) v[k] = *(const float4*)(gptr[k] + chofs);
#pragma unroll
        for (int k = 0; k < SITER; ++k) {
            if (val[k])
                *(float4*)(&tile[0][0][0] + lofs[k]) = v[k];
            else if (act[k] && p == 0)   // halo slots: zero once, stay zero
                *(float4*)(&tile[0][0][0] + lofs[k]) = make_float4(0.f,0.f,0.f,0.f);
        }
        __syncthreads();

        // ---- compute 8 channels from LDS ----
#pragma unroll
        for (int c = 0; c < CHP; ++c) {
            const float2 cc = *(const float2*)&tile[c][r][lcol];      // center w0,w0+1
            const float2 cs = *(const float2*)&tile[c][r + 1][lcol];  // south  w0,w0+1
            const float ccR = tile[c][r][lcol + 2];
            const float csR = tile[c][r + 1][lcol + 2];
            const float csL = tile[c][r + 1][lcol - 1];

            ssq0 += cc.x*cc.x; ssq1 += cc.y*cc.y; ssqR += ccR*ccR;
            nsq0 += cs.x*cs.x; nsq1 += cs.y*cs.y; nsqL += csL*csL; nsqR += csR*csR;
            dE0  += cc.x*cc.y; dE1  += cc.y*ccR;
            dS0  += cc.x*cs.x; dS1  += cc.y*cs.y;
            dSE0 += cc.x*cs.y; dSE1 += cc.y*csR;
            dSW0 += cc.x*csL;  dSW1 += cc.y*cs.x;
        }
        if (p + 1 < NPHASE) __syncthreads();
    }

    const float ic0 = 1.0f / fmaxf(sqrtf(ssq0), AF_EPS);
    const float ic1 = 1.0f / fmaxf(sqrtf(ssq1), AF_EPS);
    const float icR = 1.0f / fmaxf(sqrtf(ssqR), AF_EPS);
    const float is0 = 1.0f / fmaxf(sqrtf(nsq0), AF_EPS);
    const float is1 = 1.0f / fmaxf(sqrtf(nsq1), AF_EPS);
    const float isL = 1.0f / fmaxf(sqrtf(nsqL), AF_EPS);
    const float isR = 1.0f / fmaxf(sqrtf(nsqR), AF_EPS);

    const float E0  = fmaxf(dE0 *ic0*ic1, 0.0f);
    const float E1  = fmaxf(dE1 *ic1*icR, 0.0f);
    const float S0  = fmaxf(dS0 *ic0*is0, 0.0f);
    const float S1  = fmaxf(dS1 *ic1*is1, 0.0f);
    const float SE0 = fmaxf(dSE0*ic0*is1, 0.0f);
    const float SE1 = fmaxf(dSE1*ic1*isR, 0.0f);
    const float SW0 = fmaxf(dSW0*ic0*isL, 0.0f);
    const float SW1 = fmaxf(dSW1*ic1*is0, 0.0f);

    float* obase = out + (size_t)b * 8 * AF_PLANE + (size_t)h * AF_W + w0;
    const bool vR2 = (w0 + 2) < AF_W;
    const bool vL  = w0 > 0;
    const bool vS  = (h + 1) < AF_H;

    *(float2*)(obase + 4*AF_PLANE) = make_float2(E0, E1);
    *(float2*)(obase + 5*AF_PLANE) = make_float2(SW0, SW1);
    *(float2*)(obase + 6*AF_PLANE) = make_float2(S0, S1);
    *(float2*)(obase + 7*AF_PLANE) = make_float2(SE0, SE1);

    // a=3 (W): W(h,w) = E(h,w-1)
    float* p3 = obase + 3*AF_PLANE;
    p3[1] = E0;
    if (vR2) p3[2] = E1;
    if (!vL) p3[0] = 0.0f;

    if (vS) {
        float* onb = obase + AF_W;      // row h+1
        *(float2*)(onb + 1*AF_PLANE) = make_float2(S0, S1);   // N
        float* p0 = onb;                // NW(h+1,w) = SE(h,w-1)
        p0[1] = SE0;
        if (vR2) p0[2] = SE1;
        if (!vL) p0[0] = 0.0f;
        float* p2 = onb + 2*AF_PLANE;   // NE(h+1,w) = SW(h,w+1)
        if (vL) p2[-1] = SW0;
        p2[0] = SW1;
        if (!vR2) p2[1] = 0.0f;
    }

    if (h == 0) {                        // N/NW/NE at h=0 all OOB
        float* oz = out + (size_t)b * 8 * AF_PLANE + w0;
        const float2 z2 = make_float2(0.0f, 0.0f);
        *(float2*)(oz + 0*AF_PLANE) = z2;
        *(float2*)(oz + 1*AF_PLANE) = z2;
        *(float2*)(oz + 2*AF_PLANE) = z2;
    }
}

extern "C" void kernel_launch(void* const* d_in, const int* in_sizes, int n_in,
                              void* d_out, int out_size, void* d_ws, size_t ws_size,
                              hipStream_t stream) {
    const float* f = (const float*)d_in[0];
    float* out = (float*)d_out;
    // grid = 4 batches x 32 h-bands x 8 w-bands = 1024 blocks of 256 threads
    affinity_bulk_kernel<<<1024, 256, 0, stream>>>(f, out);
}

// Round 8
// 27.454 us; speedup vs baseline: 2.3675x; 1.6321x over previous
//
#include <hip/hip_runtime.h>

// AffinityFeature: out[b][a][h][w] = relu(cos(feat[b,:,h,w], feat[b,:,h+dh,w+dw])), 0 if OOB.
// a: 0:NW 1:N 2:NE 3:W 4:E 5:SW 6:S 7:SE. Symmetric: compute E,S,SE,SW per
// pixel, scatter mirrors to the neighbor's location.
// R8: NO LDS, NO barriers. 2 px/thread -> 4096 waves (4/SIMD TLP), channel
// loads batched x4 into statically-indexed register arrays (~20 loads in
// flight per wave). Block = one image row; per-thread-constant edge masks.

#define AF_B 4
#define AF_C 32
#define AF_H 256
#define AF_W 512
#define AF_EPS 1e-12f
#define AF_PLANE ((size_t)AF_H * AF_W)
#define CB 4   // channels per register batch

__global__ __launch_bounds__(256, 4) void affinity_reg_kernel(const float* __restrict__ f,
                                                              float* __restrict__ out) {
    // XCD-aware swizzle: 1024 blocks (one row each) -> 128-row slab per XCD
    const int cpx = gridDim.x >> 3;
    const int bid = ((int)blockIdx.x & 7) * cpx + ((int)blockIdx.x >> 3);
    const int h = bid & (AF_H - 1);
    const int b = bid >> 8;

    const int tid = (int)threadIdx.x;
    const int w0 = tid << 1;                 // 0,2,...,510

    const bool vR2 = (w0 + 2) < AF_W;        // col w0+2 exists
    const bool vL  = w0 > 0;                 // col w0-1 exists
    const bool vS  = (h + 1) < AF_H;         // south row exists
    const float mS  = vS ? 1.0f : 0.0f;
    const float mR  = vR2 ? 1.0f : 0.0f;
    const float mRS = mR * mS;
    const float mLS = (vL ? 1.0f : 0.0f) * mS;
    const int offR = vR2 ? 2 : 0;
    const int offL = vL ? -1 : 0;

    const float* pc = f + (size_t)b * AF_C * AF_PLANE + (size_t)h * AF_W + w0;
    const float* ps = pc + (vS ? AF_W : 0);

    float ssq0=0, ssq1=0, ssqR=0;
    float nsq0=0, nsq1=0, nsqL=0, nsqR=0;
    float dE0=0, dE1=0, dS0=0, dS1=0, dSE0=0, dSE1=0, dSW0=0, dSW1=0;

#pragma unroll
    for (int gch = 0; gch < AF_C / CB; ++gch) {
        // ---- issue all 20 loads of this 4-channel batch back-to-back ----
        float2 cc[CB], cs[CB];
        float aR[CB], aL[CB], aRS[CB];
#pragma unroll
        for (int k = 0; k < CB; ++k) {
            const float* p = pc + (size_t)(gch * CB + k) * AF_PLANE;
            const float* q = ps + (size_t)(gch * CB + k) * AF_PLANE;
            cc[k]  = *(const float2*)p;
            aR[k]  = p[offR];
            cs[k]  = *(const float2*)q;
            aL[k]  = q[offL];
            aRS[k] = q[offR];
        }
        // ---- consume ----
#pragma unroll
        for (int k = 0; k < CB; ++k) {
            const float ccx = cc[k].x, ccy = cc[k].y;
            const float ccR = aR[k] * mR;
            const float csx = cs[k].x * mS, csy = cs[k].y * mS;
            const float csL = aL[k] * mLS, csR = aRS[k] * mRS;

            ssq0 += ccx*ccx; ssq1 += ccy*ccy; ssqR += ccR*ccR;
            nsq0 += csx*csx; nsq1 += csy*csy; nsqL += csL*csL; nsqR += csR*csR;
            dE0  += ccx*ccy; dE1  += ccy*ccR;
            dS0  += ccx*csx; dS1  += ccy*csy;
            dSE0 += ccx*csy; dSE1 += ccy*csR;
            dSW0 += ccx*csL; dSW1 += ccy*csx;
        }
    }

    const float ic0 = 1.0f / fmaxf(sqrtf(ssq0), AF_EPS);
    const float ic1 = 1.0f / fmaxf(sqrtf(ssq1), AF_EPS);
    const float icR = 1.0f / fmaxf(sqrtf(ssqR), AF_EPS);
    const float is0 = 1.0f / fmaxf(sqrtf(nsq0), AF_EPS);
    const float is1 = 1.0f / fmaxf(sqrtf(nsq1), AF_EPS);
    const float isL = 1.0f / fmaxf(sqrtf(nsqL), AF_EPS);
    const float isR = 1.0f / fmaxf(sqrtf(nsqR), AF_EPS);

    const float E0  = fmaxf(dE0 *ic0*ic1, 0.0f);
    const float E1  = fmaxf(dE1 *ic1*icR, 0.0f);
    const float S0  = fmaxf(dS0 *ic0*is0, 0.0f);
    const float S1  = fmaxf(dS1 *ic1*is1, 0.0f);
    const float SE0 = fmaxf(dSE0*ic0*is1, 0.0f);
    const float SE1 = fmaxf(dSE1*ic1*isR, 0.0f);
    const float SW0 = fmaxf(dSW0*ic0*isL, 0.0f);
    const float SW1 = fmaxf(dSW1*ic1*is0, 0.0f);

    float* obase = out + (size_t)b * 8 * AF_PLANE + (size_t)h * AF_W + w0;

    // forward channels at (h, w0..w0+1)
    *(float2*)(obase + 4*AF_PLANE) = make_float2(E0, E1);
    *(float2*)(obase + 5*AF_PLANE) = make_float2(SW0, SW1);
    *(float2*)(obase + 6*AF_PLANE) = make_float2(S0, S1);
    *(float2*)(obase + 7*AF_PLANE) = make_float2(SE0, SE1);

    // a=3 (W): W(h,w) = E(h,w-1)
    float* p3 = obase + 3*AF_PLANE;
    p3[1] = E0;
    if (vR2) p3[2] = E1;
    if (!vL) p3[0] = 0.0f;

    if (vS) {
        float* onb = obase + AF_W;      // row h+1
        *(float2*)(onb + 1*AF_PLANE) = make_float2(S0, S1);   // N
        float* p0 = onb;                // NW(h+1,w) = SE(h,w-1)
        p0[1] = SE0;
        if (vR2) p0[2] = SE1;
        if (!vL) p0[0] = 0.0f;
        float* p2 = onb + 2*AF_PLANE;   // NE(h+1,w) = SW(h,w+1)
        if (vL) p2[-1] = SW0;
        p2[0] = SW1;
        if (!vR2) p2[1] = 0.0f;
    }

    if (h == 0) {                        // N/NW/NE at h=0 all OOB
        float* oz = out + (size_t)b * 8 * AF_PLANE + w0;
        const float2 z2 = make_float2(0.0f, 0.0f);
        *(float2*)(oz + 0*AF_PLANE) = z2;
        *(float2*)(oz + 1*AF_PLANE) = z2;
        *(float2*)(oz + 2*AF_PLANE) = z2;
    }
}

extern "C" void kernel_launch(void* const* d_in, const int* in_sizes, int n_in,
                              void* d_out, int out_size, void* d_ws, size_t ws_size,
                              hipStream_t stream) {
    const float* f = (const float*)d_in[0];
    float* out = (float*)d_out;
    // 1024 blocks = 4 batches x 256 rows; 256 threads x 2 px = one row each
    affinity_reg_kernel<<<1024, 256, 0, stream>>>(f, out);
}